// Round 1
// baseline (383.109 us; speedup 1.0000x reference)
//
#include <hip/hip_runtime.h>

#define D 1024
#define B 32
#define NI 1024
#define PP 1000
#define R 3

__device__ __forceinline__ float wred(float x) {
    #pragma unroll
    for (int off = 32; off; off >>= 1) x += __shfl_xor(x, off, 64);
    return x;
}

// K1: q_all[r,b,o] = dot(W_agg[r,o,:], vhat[b,:])  — wave handles 2 rows (r,o), all 32 b in regs
__global__ __launch_bounds__(256) void k1_qall(const float* __restrict__ Wagg,
        const float* __restrict__ vhat, float* __restrict__ qall) {
    const int w = threadIdx.x >> 6, lane = threadIdx.x & 63;
    const int row0 = (blockIdx.x * 4 + w) * 2;
    if (row0 >= R * D) return;
    const int r = row0 >> 10;
    const float* w0 = Wagg + (size_t)row0 * D;
    float acc[2][32];
    #pragma unroll
    for (int i = 0; i < 2; ++i)
        #pragma unroll
        for (int b = 0; b < 32; ++b) acc[i][b] = 0.f;
    #pragma unroll
    for (int kk = 0; kk < 4; ++kk) {
        const int col = 4 * lane + 256 * kk;
        float4 a0 = *(const float4*)(w0 + col);
        float4 a1 = *(const float4*)(w0 + D + col);
        #pragma unroll
        for (int b = 0; b < 32; ++b) {
            float4 x = *(const float4*)(vhat + b * D + col);
            acc[0][b] += a0.x*x.x + a0.y*x.y + a0.z*x.z + a0.w*x.w;
            acc[1][b] += a1.x*x.x + a1.y*x.y + a1.z*x.z + a1.w*x.w;
        }
    }
    #pragma unroll
    for (int i = 0; i < 2; ++i) {
        float mine = 0.f;
        #pragma unroll
        for (int b = 0; b < 32; ++b) {
            float s = wred(acc[i][b]);
            if (lane == b) mine = s;
        }
        const int o = (row0 + i) & 1023;
        if (lane < 32) qall[((size_t)r * B + lane) * D + o] = mine;
    }
}

// K2: scores[r,b,p] = scale * dot(q_all[r,b,:], pool[p,:]) — wave per (r, 4-p group), 32 b in regs
__global__ __launch_bounds__(256) void k2_scores(const float* __restrict__ qall,
        const float* __restrict__ pool, float* __restrict__ scores) {
    const int w = threadIdx.x >> 6, lane = threadIdx.x & 63;
    const int wid = blockIdx.x * 4 + w;
    if (wid >= R * 250) return;
    const int r = wid / 250, pg = wid % 250;
    const int p0 = pg * 4;
    const float* q0 = qall + (size_t)r * B * D;
    float acc[32][4];
    #pragma unroll
    for (int b = 0; b < 32; ++b)
        #pragma unroll
        for (int pp = 0; pp < 4; ++pp) acc[b][pp] = 0.f;
    #pragma unroll
    for (int kk = 0; kk < 4; ++kk) {
        const int col = 4 * lane + 256 * kk;
        float4 pv[4];
        #pragma unroll
        for (int pp = 0; pp < 4; ++pp) pv[pp] = *(const float4*)(pool + (size_t)(p0 + pp) * D + col);
        #pragma unroll
        for (int b = 0; b < 32; ++b) {
            float4 q = *(const float4*)(q0 + b * D + col);
            #pragma unroll
            for (int pp = 0; pp < 4; ++pp)
                acc[b][pp] += q.x*pv[pp].x + q.y*pv[pp].y + q.z*pv[pp].z + q.w*pv[pp].w;
        }
    }
    const float scale = 0.03125f;
    #pragma unroll
    for (int pp = 0; pp < 4; ++pp) {
        float mine = 0.f;
        #pragma unroll
        for (int b = 0; b < 32; ++b) {
            float s = wred(acc[b][pp]);
            if (lane == b) mine = s;
        }
        if (lane < 32) scores[((size_t)r * B + lane) * PP + p0 + pp] = mine * scale;
    }
}

// K3: softmax over p per (r,b) row — block per row
__global__ __launch_bounds__(256) void k3_softmax(const float* __restrict__ scores,
        float* __restrict__ weights) {
    const int rb = blockIdx.x;
    const float* srow = scores + (size_t)rb * PP;
    float* wrow = weights + (size_t)rb * PP;
    __shared__ float red[8];
    const int tid = threadIdx.x, w = tid >> 6, lane = tid & 63;
    float v[4];
    float mx = -1e30f;
    #pragma unroll
    for (int i = 0; i < 4; ++i) {
        int p = tid + 256 * i;
        v[i] = (p < PP) ? srow[p] : -1e30f;
        mx = fmaxf(mx, v[i]);
    }
    #pragma unroll
    for (int off = 32; off; off >>= 1) mx = fmaxf(mx, __shfl_xor(mx, off, 64));
    if (lane == 0) red[w] = mx;
    __syncthreads();
    mx = fmaxf(fmaxf(red[0], red[1]), fmaxf(red[2], red[3]));
    float e[4], sum = 0.f;
    #pragma unroll
    for (int i = 0; i < 4; ++i) { e[i] = __expf(v[i] - mx); sum += e[i]; }
    sum = wred(sum);
    if (lane == 0) red[4 + w] = sum;
    __syncthreads();
    const float inv = 1.f / (red[4] + red[5] + red[6] + red[7]);
    #pragma unroll
    for (int i = 0; i < 4; ++i) {
        int p = tid + 256 * i;
        if (p < PP) wrow[p] = e[i] * inv;
    }
}

// K4: v_agg[b,d] = (1/3) * sum_r sum_p weights[r,b,p] * pool[p,d] — block per (b, half of d)
__global__ __launch_bounds__(256) void k4_vagg(const float* __restrict__ weights,
        const float* __restrict__ pool, float* __restrict__ vagg) {
    const int b = blockIdx.x >> 1, dh = blockIdx.x & 1;
    const int d = dh * 512 + threadIdx.x * 2;
    __shared__ float lw[PP];
    for (int p = threadIdx.x; p < PP; p += 256)
        lw[p] = (weights[(size_t)b * PP + p] + weights[(size_t)(B + b) * PP + p] +
                 weights[(size_t)(2 * B + b) * PP + p]) * (1.f / 3.f);
    __syncthreads();
    float2 acc = {0.f, 0.f};
    for (int p = 0; p < PP; ++p) {
        float2 pv = *(const float2*)(pool + (size_t)p * D + d);
        float wv = lw[p];
        acc.x += wv * pv.x; acc.y += wv * pv.y;
    }
    *(float2*)(vagg + (size_t)b * D + d) = acc;
}

// K5: q = vhat@Wq.T + bq ; k = vagg@Wk.T + bk ; v = vagg@Wv.T + bv — wave per 2 rows, 32 b in regs
__global__ __launch_bounds__(256) void k5_qkv(const float* __restrict__ Wq, const float* __restrict__ bq,
        const float* __restrict__ Wk, const float* __restrict__ bk,
        const float* __restrict__ Wv, const float* __restrict__ bv,
        const float* __restrict__ vhat, const float* __restrict__ vagg,
        float* __restrict__ qout, float* __restrict__ kout, float* __restrict__ vout) {
    const int w = threadIdx.x >> 6, lane = threadIdx.x & 63;
    const int row0 = (blockIdx.x * 4 + w) * 2;
    if (row0 >= 3 * D) return;
    const int kind = row0 >> 10;
    const int o0 = row0 & 1023;
    const float* Wm = kind == 0 ? Wq : (kind == 1 ? Wk : Wv);
    const float* bias = kind == 0 ? bq : (kind == 1 ? bk : bv);
    const float* x = kind == 0 ? vhat : vagg;
    float* out = kind == 0 ? qout : (kind == 1 ? kout : vout);
    const float* w0 = Wm + (size_t)o0 * D;
    float acc[2][32];
    #pragma unroll
    for (int i = 0; i < 2; ++i)
        #pragma unroll
        for (int b = 0; b < 32; ++b) acc[i][b] = 0.f;
    #pragma unroll
    for (int kk = 0; kk < 4; ++kk) {
        const int col = 4 * lane + 256 * kk;
        float4 a0 = *(const float4*)(w0 + col);
        float4 a1 = *(const float4*)(w0 + D + col);
        #pragma unroll
        for (int b = 0; b < 32; ++b) {
            float4 xv = *(const float4*)(x + b * D + col);
            acc[0][b] += a0.x*xv.x + a0.y*xv.y + a0.z*xv.z + a0.w*xv.w;
            acc[1][b] += a1.x*xv.x + a1.y*xv.y + a1.z*xv.z + a1.w*xv.w;
        }
    }
    #pragma unroll
    for (int i = 0; i < 2; ++i) {
        float mine = 0.f;
        #pragma unroll
        for (int b = 0; b < 32; ++b) {
            float s = wred(acc[i][b]);
            if (lane == b) mine = s;
        }
        const int o = o0 + i;
        if (lane < 32) out[(size_t)lane * D + o] = mine + bias[o];
    }
}

// K6: sim[b] = scale * dot(q[b],k[b]); u[b,:] = vhat[b,:] - sigmoid(sim)*v[b,:] — wave per b
__global__ __launch_bounds__(256) void k6_u(const float* __restrict__ qb, const float* __restrict__ kb,
        const float* __restrict__ vb, const float* __restrict__ vhat, float* __restrict__ u) {
    const int w = threadIdx.x >> 6, lane = threadIdx.x & 63;
    const int b = blockIdx.x * 4 + w;
    float acc = 0.f;
    #pragma unroll
    for (int kk = 0; kk < 4; ++kk) {
        const int col = 4 * lane + 256 * kk;
        float4 q = *(const float4*)(qb + (size_t)b * D + col);
        float4 k = *(const float4*)(kb + (size_t)b * D + col);
        acc += q.x*k.x + q.y*k.y + q.z*k.z + q.w*k.w;
    }
    acc = wred(acc);
    const float sig = 1.f / (1.f + __expf(-acc * 0.03125f));
    #pragma unroll
    for (int kk = 0; kk < 4; ++kk) {
        const int col = 4 * lane + 256 * kk;
        float4 vh = *(const float4*)(vhat + (size_t)b * D + col);
        float4 vv = *(const float4*)(vb + (size_t)b * D + col);
        float4 o;
        o.x = vh.x - sig * vv.x; o.y = vh.y - sig * vv.y;
        o.z = vh.z - sig * vv.z; o.w = vh.w - sig * vv.w;
        *(float4*)(u + (size_t)b * D + col) = o;
    }
}

// K7: v_diff[b,o] = relu(dot(Wc[o,:], u[b,:]) + bc[o]) — wave per 2 rows, 32 b in regs
__global__ __launch_bounds__(256) void k7_vdiff(const float* __restrict__ Wc, const float* __restrict__ bc,
        const float* __restrict__ u, float* __restrict__ vdiff) {
    const int w = threadIdx.x >> 6, lane = threadIdx.x & 63;
    const int row0 = (blockIdx.x * 4 + w) * 2;
    if (row0 >= D) return;
    const float* w0 = Wc + (size_t)row0 * D;
    float acc[2][32];
    #pragma unroll
    for (int i = 0; i < 2; ++i)
        #pragma unroll
        for (int b = 0; b < 32; ++b) acc[i][b] = 0.f;
    #pragma unroll
    for (int kk = 0; kk < 4; ++kk) {
        const int col = 4 * lane + 256 * kk;
        float4 a0 = *(const float4*)(w0 + col);
        float4 a1 = *(const float4*)(w0 + D + col);
        #pragma unroll
        for (int b = 0; b < 32; ++b) {
            float4 xv = *(const float4*)(u + b * D + col);
            acc[0][b] += a0.x*xv.x + a0.y*xv.y + a0.z*xv.z + a0.w*xv.w;
            acc[1][b] += a1.x*xv.x + a1.y*xv.y + a1.z*xv.z + a1.w*xv.w;
        }
    }
    #pragma unroll
    for (int i = 0; i < 2; ++i) {
        float mine = 0.f;
        #pragma unroll
        for (int b = 0; b < 32; ++b) {
            float s = wred(acc[i][b]);
            if (lane == b) mine = s;
        }
        const int o = row0 + i;
        if (lane < 32) vdiff[(size_t)lane * D + o] = fmaxf(mine + bc[o], 0.f);
    }
}

// K8: cb[b] = dot(v_diff[b,:], Wg2) + bg — wave per b
__global__ __launch_bounds__(256) void k8_cb(const float* __restrict__ vdiff,
        const float* __restrict__ Wg, const float* __restrict__ bg, float* __restrict__ cb) {
    const int w = threadIdx.x >> 6, lane = threadIdx.x & 63;
    const int b = blockIdx.x * 4 + w;
    const float* Wg2 = Wg + D;
    float acc = 0.f;
    #pragma unroll
    for (int kk = 0; kk < 4; ++kk) {
        const int col = 4 * lane + 256 * kk;
        float4 vd = *(const float4*)(vdiff + (size_t)b * D + col);
        float4 g2 = *(const float4*)(Wg2 + col);
        acc += vd.x*g2.x + vd.y*g2.y + vd.z*g2.z + vd.w*g2.w;
    }
    acc = wred(acc);
    if (lane == 0) cb[b] = acc + bg[0];
}

// K9: out[b,n,d] = att + rs * sigmoid(att[b,n,:]·Wg1 + cb[b]) * vdiff[b,d] — wave per (b,n) row
__global__ __launch_bounds__(256) void k9_main(const float* __restrict__ att,
        const float* __restrict__ Wg, const float* __restrict__ cb,
        const float* __restrict__ vdiff, const float* __restrict__ rs_p,
        float* __restrict__ out) {
    const int w = threadIdx.x >> 6, lane = threadIdx.x & 63;
    const size_t row = (size_t)blockIdx.x * 4 + w;
    const int b = (int)(row >> 10);
    const float* arow = att + row * D;
    float4 a[4];
    float acc = 0.f;
    #pragma unroll
    for (int kk = 0; kk < 4; ++kk) {
        const int col = 4 * lane + 256 * kk;
        a[kk] = *(const float4*)(arow + col);
        float4 g = *(const float4*)(Wg + col);
        acc += a[kk].x*g.x + a[kk].y*g.y + a[kk].z*g.z + a[kk].w*g.w;
    }
    acc = wred(acc) + cb[b];
    const float gv = 1.f / (1.f + __expf(-acc));
    const float grs = gv * rs_p[0];
    float* orow = out + row * D;
    #pragma unroll
    for (int kk = 0; kk < 4; ++kk) {
        const int col = 4 * lane + 256 * kk;
        float4 vd = *(const float4*)(vdiff + (size_t)b * D + col);
        float4 o;
        o.x = a[kk].x + grs * vd.x; o.y = a[kk].y + grs * vd.y;
        o.z = a[kk].z + grs * vd.z; o.w = a[kk].w + grs * vd.w;
        *(float4*)(orow + col) = o;
    }
}

extern "C" void kernel_launch(void* const* d_in, const int* in_sizes, int n_in,
                              void* d_out, int out_size, void* d_ws, size_t ws_size,
                              hipStream_t stream) {
    const float* att  = (const float*)d_in[0];
    const float* fc   = (const float*)d_in[1];
    const float* pool = (const float*)d_in[2];
    const float* Wagg = (const float*)d_in[3];
    const float* Wq   = (const float*)d_in[4];
    const float* bq   = (const float*)d_in[5];
    const float* Wk   = (const float*)d_in[6];
    const float* bk   = (const float*)d_in[7];
    const float* Wv   = (const float*)d_in[8];
    const float* bv   = (const float*)d_in[9];
    const float* Wc   = (const float*)d_in[10];
    const float* bc   = (const float*)d_in[11];
    const float* Wg   = (const float*)d_in[12];
    const float* bg   = (const float*)d_in[13];
    const float* rs   = (const float*)d_in[14];
    float* out = (float*)d_out;

    float* ws      = (float*)d_ws;
    float* qall    = ws;                  // R*B*D   = 98304
    float* scores  = qall + R * B * D;    // R*B*PP  = 96000
    float* weights = scores + R * B * PP; // 96000
    float* vagg    = weights + R * B * PP;// B*D = 32768
    float* qb      = vagg + B * D;
    float* kb      = qb + B * D;
    float* vb      = kb + B * D;
    float* ub      = vb + B * D;
    float* vdiff   = ub + B * D;
    float* cb      = vdiff + B * D;       // 32

    k1_qall<<<384, 256, 0, stream>>>(Wagg, fc, qall);
    k2_scores<<<188, 256, 0, stream>>>(qall, pool, scores);
    k3_softmax<<<R * B, 256, 0, stream>>>(scores, weights);
    k4_vagg<<<B * 2, 256, 0, stream>>>(weights, pool, vagg);
    k5_qkv<<<384, 256, 0, stream>>>(Wq, bq, Wk, bk, Wv, bv, fc, vagg, qb, kb, vb);
    k6_u<<<8, 256, 0, stream>>>(qb, kb, vb, fc, ub);
    k7_vdiff<<<128, 256, 0, stream>>>(Wc, bc, ub, vdiff);
    k8_cb<<<8, 256, 0, stream>>>(vdiff, Wg, bg, cb);
    k9_main<<<B * NI / 4, 256, 0, stream>>>(att, Wg, cb, vdiff, rs, out);
}

// Round 2
// 257.806 us; speedup vs baseline: 1.4860x; 1.4860x over previous
//
#include <hip/hip_runtime.h>

#define D 1024
#define B 32
#define NI 1024
#define PP 1000
#define R 3
#define SPLITS 4        // split-K factor for all GEMMs (K chunk = 256 = 8 BK tiles)
#define BK 32
#define PAD 34          // row pad (floats): b64 reads land 2-way-conflict only (free)

__device__ __forceinline__ float wred(float x) {
    #pragma unroll
    for (int off = 32; off; off >>= 1) x += __shfl_xor(x, off, 64);
    return x;
}

// ---------------------------------------------------------------------------
// Tiled GEMM core: C[m, b] = sum_k A[m, k] * X[b, k]
//   BM=128 rows per block, BN=32 (all batches), BK=32, 256 threads,
//   micro-tile 4m x 4b per thread. K-range [kc0, kc0+256).
//   X rows may be a sum of NXS partial buffers (stride xss floats apart).
// ---------------------------------------------------------------------------
template<int NXS>
__device__ __forceinline__ void gemm_core(
        const float* __restrict__ A, int mbase, int Mrows,
        const float* __restrict__ Xb, int xrstride, size_t xss,
        int kc0, float acc[4][4]) {
    __shared__ float Ws[128][PAD];
    __shared__ float Xs[32][PAD];
    const int t = threadIdx.x;
    const int ty = t >> 3, tx = t & 7;   // ty 0..31, tx 0..7
    const int m0 = 4 * ty, b0 = 4 * tx;
    const int lrow = t >> 3, lq = t & 7; // staging: row 0..31, float4 idx 0..7

    #pragma unroll
    for (int i = 0; i < 4; ++i)
        #pragma unroll
        for (int j = 0; j < 4; ++j) acc[i][j] = 0.f;

    for (int kt = 0; kt < 8; ++kt) {
        const int kc = kc0 + kt * BK;
        // ---- stage W tile (128 x 32) ----
        #pragma unroll
        for (int rr = 0; rr < 4; ++rr) {
            const int row = lrow + 32 * rr;
            float4 v = make_float4(0.f, 0.f, 0.f, 0.f);
            if (mbase + row < Mrows)
                v = *(const float4*)(A + (size_t)(mbase + row) * D + kc + 4 * lq);
            *(float2*)&Ws[row][4 * lq]     = make_float2(v.x, v.y);
            *(float2*)&Ws[row][4 * lq + 2] = make_float2(v.z, v.w);
        }
        // ---- stage X tile (32 x 32), summing NXS partials ----
        {
            const float* xp = Xb + (size_t)lrow * xrstride + kc + 4 * lq;
            float4 v = *(const float4*)xp;
            #pragma unroll
            for (int s = 1; s < NXS; ++s) {
                float4 w = *(const float4*)(xp + (size_t)s * xss);
                v.x += w.x; v.y += w.y; v.z += w.z; v.w += w.w;
            }
            *(float2*)&Xs[lrow][4 * lq]     = make_float2(v.x, v.y);
            *(float2*)&Xs[lrow][4 * lq + 2] = make_float2(v.z, v.w);
        }
        __syncthreads();
        // ---- compute: 16 k-pairs ----
        #pragma unroll
        for (int kp = 0; kp < 16; ++kp) {
            float2 wv[4], xv[4];
            #pragma unroll
            for (int i = 0; i < 4; ++i) wv[i] = *(const float2*)&Ws[m0 + i][2 * kp];
            #pragma unroll
            for (int j = 0; j < 4; ++j) xv[j] = *(const float2*)&Xs[b0 + j][2 * kp];
            #pragma unroll
            for (int i = 0; i < 4; ++i)
                #pragma unroll
                for (int j = 0; j < 4; ++j) {
                    acc[i][j] += wv[i].x * xv[j].x;
                    acc[i][j] += wv[i].y * xv[j].y;
                }
        }
        __syncthreads();
    }
}

// K1: qall partials. A = W_agg (3072 x 1024), X = fc (32 x 1024).
// Cp layout: [s][b][3072]
__global__ __launch_bounds__(256) void gemm_k1(const float* __restrict__ Wagg,
        const float* __restrict__ fc, float* __restrict__ Cp) {
    const int mb = blockIdx.x, s = blockIdx.y;
    const int mbase = mb * 128;
    float acc[4][4];
    gemm_core<1>(Wagg, mbase, R * D, fc, D, 0, s * 256, acc);
    const int t = threadIdx.x, ty = t >> 3, tx = t & 7;
    const int m = mbase + 4 * ty;
    #pragma unroll
    for (int j = 0; j < 4; ++j) {
        float* cp = Cp + ((size_t)(s * B) + 4 * tx + j) * (R * D) + m;
        *(float4*)cp = make_float4(acc[0][j], acc[1][j], acc[2][j], acc[3][j]);
    }
}

// K2: score partials. A = pool (1000 x 1024), X = sum_s qall partials for row r.
// Cp layout: [s][r][b][1024] (only m<1000 valid)
__global__ __launch_bounds__(256) void gemm_k2(const float* __restrict__ pool,
        const float* __restrict__ qallp, float* __restrict__ Cp) {
    const int mb = blockIdx.x, s = blockIdx.y, r = blockIdx.z;
    const int mbase = mb * 128;
    float acc[4][4];
    gemm_core<SPLITS>(pool, mbase, PP, qallp + r * D, R * D, (size_t)B * R * D,
                      s * 256, acc);
    const int t = threadIdx.x, ty = t >> 3, tx = t & 7;
    const int m = mbase + 4 * ty;
    if (m >= PP) return;
    #pragma unroll
    for (int j = 0; j < 4; ++j) {
        float* cp = Cp + ((size_t)((s * R + r) * B) + 4 * tx + j) * D + m;
        *(float4*)cp = make_float4(acc[0][j], acc[1][j], acc[2][j], acc[3][j]);
    }
}

// K5: q/k/v partials. z selects (Wq,fc) / (Wk,vagg) / (Wv,vagg).
// Cp layout: [s][kind][b][1024]
__global__ __launch_bounds__(256) void gemm_k5(const float* __restrict__ Wq,
        const float* __restrict__ Wk, const float* __restrict__ Wv,
        const float* __restrict__ fc, const float* __restrict__ vagg,
        float* __restrict__ Cp) {
    const int mb = blockIdx.x, s = blockIdx.y, z = blockIdx.z;
    const int mbase = mb * 128;
    const float* A = (z == 0) ? Wq : ((z == 1) ? Wk : Wv);
    const float* X = (z == 0) ? fc : vagg;
    float acc[4][4];
    gemm_core<1>(A, mbase, D, X, D, 0, s * 256, acc);
    const int t = threadIdx.x, ty = t >> 3, tx = t & 7;
    const int m = mbase + 4 * ty;
    #pragma unroll
    for (int j = 0; j < 4; ++j) {
        float* cp = Cp + ((size_t)((s * R + z) * B) + 4 * tx + j) * D + m;
        *(float4*)cp = make_float4(acc[0][j], acc[1][j], acc[2][j], acc[3][j]);
    }
}

// K7: v_diff pre-activation partials. A = Wc, X = u. Cp layout: [s][b][1024]
__global__ __launch_bounds__(256) void gemm_k7(const float* __restrict__ Wc,
        const float* __restrict__ u, float* __restrict__ Cp) {
    const int mb = blockIdx.x, s = blockIdx.y;
    const int mbase = mb * 128;
    float acc[4][4];
    gemm_core<1>(Wc, mbase, D, u, D, 0, s * 256, acc);
    const int t = threadIdx.x, ty = t >> 3, tx = t & 7;
    const int m = mbase + 4 * ty;
    #pragma unroll
    for (int j = 0; j < 4; ++j) {
        float* cp = Cp + ((size_t)(s * B) + 4 * tx + j) * D + m;
        *(float4*)cp = make_float4(acc[0][j], acc[1][j], acc[2][j], acc[3][j]);
    }
}

// K3: sum score partials, scale, softmax over p -> weights[(r*B+b)*PP + p]
__global__ __launch_bounds__(256) void k3_softmax(const float* __restrict__ scp,
        float* __restrict__ weights) {
    const int rb = blockIdx.x;
    const int r = rb >> 5, b = rb & 31;
    float* wrow = weights + (size_t)rb * PP;
    __shared__ float red[8];
    const int tid = threadIdx.x, w = tid >> 6, lane = tid & 63;
    float v[4];
    float mx = -1e30f;
    #pragma unroll
    for (int i = 0; i < 4; ++i) {
        const int p = tid + 256 * i;
        float x = -1e30f;
        if (p < PP) {
            x = 0.f;
            #pragma unroll
            for (int s = 0; s < SPLITS; ++s)
                x += scp[((size_t)((s * R + r) * B) + b) * D + p];
            x *= 0.03125f;
        }
        v[i] = x;
        mx = fmaxf(mx, x);
    }
    #pragma unroll
    for (int off = 32; off; off >>= 1) mx = fmaxf(mx, __shfl_xor(mx, off, 64));
    if (lane == 0) red[w] = mx;
    __syncthreads();
    mx = fmaxf(fmaxf(red[0], red[1]), fmaxf(red[2], red[3]));
    float e[4], sum = 0.f;
    #pragma unroll
    for (int i = 0; i < 4; ++i) { e[i] = __expf(v[i] - mx); sum += e[i]; }
    sum = wred(sum);
    if (lane == 0) red[4 + w] = sum;
    __syncthreads();
    const float inv = 1.f / (red[4] + red[5] + red[6] + red[7]);
    #pragma unroll
    for (int i = 0; i < 4; ++i) {
        const int p = tid + 256 * i;
        if (p < PP) wrow[p] = e[i] * inv;
    }
}

// K4: v_agg[b,d] = (1/3) * sum_p wbar[b,p] * pool[p,d]
__global__ __launch_bounds__(256) void k4_vagg(const float* __restrict__ weights,
        const float* __restrict__ pool, float* __restrict__ vagg) {
    const int b = blockIdx.x >> 1, dh = blockIdx.x & 1;
    const int d = dh * 512 + threadIdx.x * 2;
    __shared__ float lw[PP];
    for (int p = threadIdx.x; p < PP; p += 256)
        lw[p] = (weights[(size_t)b * PP + p] + weights[(size_t)(B + b) * PP + p] +
                 weights[(size_t)(2 * B + b) * PP + p]) * (1.f / 3.f);
    __syncthreads();
    float2 acc = {0.f, 0.f};
    #pragma unroll 4
    for (int p = 0; p < PP; ++p) {
        float2 pv = *(const float2*)(pool + (size_t)p * D + d);
        float wv = lw[p];
        acc.x += wv * pv.x; acc.y += wv * pv.y;
    }
    *(float2*)(vagg + (size_t)b * D + d) = acc;
}

// K6: sum qkv partials (+bias), sim = scale*dot(q,k), u = vhat - sigmoid(sim)*v
__global__ __launch_bounds__(256) void k6_u(const float* __restrict__ qkvp,
        const float* __restrict__ bq, const float* __restrict__ bk,
        const float* __restrict__ bv, const float* __restrict__ vhat,
        float* __restrict__ u) {
    const int b = blockIdx.x;
    const int t = threadIdx.x, w = t >> 6, lane = t & 63;
    const int d = 4 * t;
    float4 qv = *(const float4*)(bq + d);
    float4 kv = *(const float4*)(bk + d);
    #pragma unroll
    for (int s = 0; s < SPLITS; ++s) {
        float4 a = *(const float4*)(qkvp + ((size_t)((s * R + 0) * B) + b) * D + d);
        float4 c = *(const float4*)(qkvp + ((size_t)((s * R + 1) * B) + b) * D + d);
        qv.x += a.x; qv.y += a.y; qv.z += a.z; qv.w += a.w;
        kv.x += c.x; kv.y += c.y; kv.z += c.z; kv.w += c.w;
    }
    float local = qv.x * kv.x + qv.y * kv.y + qv.z * kv.z + qv.w * kv.w;
    local = wred(local);
    __shared__ float red[4];
    if (lane == 0) red[w] = local;
    __syncthreads();
    const float sim = (red[0] + red[1] + red[2] + red[3]) * 0.03125f;
    const float sig = 1.f / (1.f + __expf(-sim));
    float4 vv = *(const float4*)(bv + d);
    #pragma unroll
    for (int s = 0; s < SPLITS; ++s) {
        float4 c = *(const float4*)(qkvp + ((size_t)((s * R + 2) * B) + b) * D + d);
        vv.x += c.x; vv.y += c.y; vv.z += c.z; vv.w += c.w;
    }
    const float4 vh = *(const float4*)(vhat + (size_t)b * D + d);
    float4 o;
    o.x = vh.x - sig * vv.x; o.y = vh.y - sig * vv.y;
    o.z = vh.z - sig * vv.z; o.w = vh.w - sig * vv.w;
    *(float4*)(u + (size_t)b * D + d) = o;
}

// K8: vdiff[b,d] = relu(sum_s vdp + bc); cb[b] = dot(vdiff[b], Wg2) + bg
__global__ __launch_bounds__(256) void k8_cb(const float* __restrict__ vdp,
        const float* __restrict__ bc, const float* __restrict__ Wg,
        const float* __restrict__ bg, float* __restrict__ vdiff,
        float* __restrict__ cb) {
    const int b = blockIdx.x;
    const int t = threadIdx.x, w = t >> 6, lane = t & 63;
    const int d = 4 * t;
    float4 a = *(const float4*)(bc + d);
    #pragma unroll
    for (int s = 0; s < SPLITS; ++s) {
        float4 c = *(const float4*)(vdp + ((size_t)(s * B) + b) * D + d);
        a.x += c.x; a.y += c.y; a.z += c.z; a.w += c.w;
    }
    a.x = fmaxf(a.x, 0.f); a.y = fmaxf(a.y, 0.f);
    a.z = fmaxf(a.z, 0.f); a.w = fmaxf(a.w, 0.f);
    *(float4*)(vdiff + (size_t)b * D + d) = a;
    const float4 g2 = *(const float4*)(Wg + D + d);
    float local = a.x * g2.x + a.y * g2.y + a.z * g2.z + a.w * g2.w;
    local = wred(local);
    __shared__ float red[4];
    if (lane == 0) red[w] = local;
    __syncthreads();
    if (t == 0) cb[b] = red[0] + red[1] + red[2] + red[3] + bg[0];
}

// K9: out[b,n,d] = att + rs * sigmoid(att[b,n,:].Wg1 + cb[b]) * vdiff[b,d]
__global__ __launch_bounds__(256) void k9_main(const float* __restrict__ att,
        const float* __restrict__ Wg, const float* __restrict__ cb,
        const float* __restrict__ vdiff, const float* __restrict__ rs_p,
        float* __restrict__ out) {
    const int w = threadIdx.x >> 6, lane = threadIdx.x & 63;
    const size_t row = (size_t)blockIdx.x * 4 + w;
    const int b = (int)(row >> 10);
    const float* arow = att + row * D;
    float4 a[4];
    float acc = 0.f;
    #pragma unroll
    for (int kk = 0; kk < 4; ++kk) {
        const int col = 4 * lane + 256 * kk;
        a[kk] = *(const float4*)(arow + col);
        float4 g = *(const float4*)(Wg + col);
        acc += a[kk].x * g.x + a[kk].y * g.y + a[kk].z * g.z + a[kk].w * g.w;
    }
    acc = wred(acc) + cb[b];
    const float gv = 1.f / (1.f + __expf(-acc));
    const float grs = gv * rs_p[0];
    float* orow = out + row * D;
    #pragma unroll
    for (int kk = 0; kk < 4; ++kk) {
        const int col = 4 * lane + 256 * kk;
        float4 vd = *(const float4*)(vdiff + (size_t)b * D + col);
        float4 o;
        o.x = a[kk].x + grs * vd.x; o.y = a[kk].y + grs * vd.y;
        o.z = a[kk].z + grs * vd.z; o.w = a[kk].w + grs * vd.w;
        *(float4*)(orow + col) = o;
    }
}

extern "C" void kernel_launch(void* const* d_in, const int* in_sizes, int n_in,
                              void* d_out, int out_size, void* d_ws, size_t ws_size,
                              hipStream_t stream) {
    const float* att  = (const float*)d_in[0];
    const float* fc   = (const float*)d_in[1];
    const float* pool = (const float*)d_in[2];
    const float* Wagg = (const float*)d_in[3];
    const float* Wq   = (const float*)d_in[4];
    const float* bq   = (const float*)d_in[5];
    const float* Wk   = (const float*)d_in[6];
    const float* bk   = (const float*)d_in[7];
    const float* Wv   = (const float*)d_in[8];
    const float* bv   = (const float*)d_in[9];
    const float* Wc   = (const float*)d_in[10];
    const float* bc   = (const float*)d_in[11];
    const float* Wg   = (const float*)d_in[12];
    const float* bg   = (const float*)d_in[13];
    const float* rs   = (const float*)d_in[14];
    float* out = (float*)d_out;

    float* ws = (float*)d_ws;
    float* qallp   = ws;                              // SPLITS*B*3072 = 393216
    float* scp     = qallp + (size_t)SPLITS * B * R * D;  // SPLITS*R*B*1024 = 393216
    float* weights = scp + (size_t)SPLITS * R * B * D;    // R*B*PP = 96000
    float* vagg    = weights + (size_t)R * B * PP;        // B*D
    float* qkvp    = vagg + (size_t)B * D;                // SPLITS*R*B*1024 = 393216
    float* ub      = qkvp + (size_t)SPLITS * R * B * D;   // B*D
    float* vdp     = ub + (size_t)B * D;                  // SPLITS*B*1024 = 131072
    float* vdiff   = vdp + (size_t)SPLITS * B * D;        // B*D
    float* cbuf    = vdiff + (size_t)B * D;               // B

    gemm_k1<<<dim3(24, SPLITS), 256, 0, stream>>>(Wagg, fc, qallp);
    gemm_k2<<<dim3(8, SPLITS, R), 256, 0, stream>>>(pool, qallp, scp);
    k3_softmax<<<R * B, 256, 0, stream>>>(scp, weights);
    k4_vagg<<<B * 2, 256, 0, stream>>>(weights, pool, vagg);
    gemm_k5<<<dim3(8, SPLITS, R), 256, 0, stream>>>(Wq, Wk, Wv, fc, vagg, qkvp);
    k6_u<<<B, 256, 0, stream>>>(qkvp, bq, bk, bv, fc, ub);
    gemm_k7<<<dim3(8, SPLITS), 256, 0, stream>>>(Wc, ub, vdp);
    k8_cb<<<B, 256, 0, stream>>>(vdp, bc, Wg, bg, vdiff, cbuf);
    k9_main<<<B * NI / 4, 256, 0, stream>>>(att, Wg, cbuf, vdiff, rs, out);
}